// Round 7
// baseline (4884.769 us; speedup 1.0000x reference)
//
#include <hip/hip_runtime.h>

#define BATCHES 8
#define NPTS 2048
#define RPT 4
#define NITERS 50

__device__ __forceinline__ float fexp2(float x) {
#if __has_builtin(__builtin_amdgcn_exp2f)
    return __builtin_amdgcn_exp2f(x);
#else
    return exp2f(x);
#endif
}

// Per-batch phase-counter barrier (monotonic counter, no reset race).
// Validated on HW in R2 (passed, absmax 0.0) at 2 blocks/CU.
__device__ __forceinline__ void batch_barrier(int* cnt, int expected) {
    __syncthreads();
    if (threadIdx.x == 0) {
        __threadfence();  // release: publish prior global stores (L2 wb)
        __hip_atomic_fetch_add(cnt, 1, __ATOMIC_RELAXED, __HIP_MEMORY_SCOPE_AGENT);
        while (__hip_atomic_load(cnt, __ATOMIC_RELAXED, __HIP_MEMORY_SCOPE_AGENT) < expected)
            __builtin_amdgcn_s_sleep(2);
        __threadfence();  // acquire (L2 inv)
    }
    __syncthreads();
}

// One LDS buffer (32 KB), restaged per half-iteration from global (L2/L3-hot).
// TPB threads, NSL lanes per row-group, BPB blocks per batch.
template<int TPB, int NSL, int BPB>
__global__ __launch_bounds__(TPB, 4)
void emd_sinkhorn(const float* __restrict__ preds, const float* __restrict__ gts,
                  float* __restrict__ out, float* __restrict__ ws)
{
    constexpr int GROUPS = TPB / NSL;    // row-groups per block
    constexpr int RPB = GROUPS * RPT;    // rows per block
    static_assert(RPB * BPB == NPTS, "row coverage");

    // eps = 0.005, N = M = 2048
    const float ALPHA = 288.53900817779268f;     // log2(e)/eps
    const float TWOA  = 2.f * ALPHA;
    const float EL2   = 0.0034657359027997266f;  // eps*ln2
    const float FC    = -0.038123094930796992f;  // eps*log_mu = -eps*ln(2048)

    float* fdual = ws;                       // [BATCHES*NPTS]
    float* gdual = ws + BATCHES * NPTS;      // [BATCHES*NPTS]
    int*   cnts  = (int*)(ws + 2 * BATCHES * NPTS);  // 8 counters, stride 64 ints
    // duals + counters zeroed by host hipMemsetAsync (stream-ordered before us)

    const int batch = blockIdx.x & (BATCHES - 1);
    const int chunk = blockIdx.x >> 3;           // 0..BPB-1
    const int tid = threadIdx.x;
    const int rg  = tid / NSL;                   // row-group
    const int sl  = tid % NSL;                   // j-slice lane
    const int row0 = chunk * RPB + rg * RPT;
    const int dbase = batch * NPTS;
    int* cnt = &cnts[batch * 64];

    __shared__ float4 sT[NPTS];                  // 32 KB: current pass's cloud + a_j

    const float* pb = preds + (size_t)dbase * 3;
    const float* gb = gts   + (size_t)dbase * 3;

    // Per-thread row constants (points never change), read once from global.
    float rx[RPT], ry[RPT], rz[RPT], pp[RPT], ff[RPT];
    float gx[RPT], gy[RPT], gz[RPT], qq[RPT];
#pragma unroll
    for (int r = 0; r < RPT; ++r) {
        const int i = row0 + r;
        float px = pb[3*i], py = pb[3*i+1], pz = pb[3*i+2];
        rx[r] = TWOA * px; ry[r] = TWOA * py; rz[r] = TWOA * pz;
        pp[r] = px*px + py*py + pz*pz;
        float qx = gb[3*i], qy = gb[3*i+1], qz = gb[3*i+2];
        gx[r] = TWOA * qx; gy[r] = TWOA * qy; gz[r] = TWOA * qz;
        qq[r] = qx*qx + qy*qy + qz*qz;
    }

    int phase = 0;
    float m[RPT], Ss[RPT];

    for (int it = 0; it < NITERS; ++it) {
        // ---- stage G-cloud: sT[j] = (qx,qy,qz, ALPHA*(g_j - |q|^2)) ----
        for (int idx = tid; idx < NPTS; idx += TPB) {
            float x = gb[3*idx], y = gb[3*idx+1], z = gb[3*idx+2];
            float d = gdual[dbase + idx];
            sT[idx] = make_float4(x, y, z, ALPHA * (d - (x*x + y*y + z*z)));
        }
        __syncthreads();
        // ---- f-pass: f_i = FC + |p|^2 - EL2*(max_j t + log2 sum 2^(t-max)) ----
#pragma unroll
        for (int r = 0; r < RPT; ++r) m[r] = -3.4e38f;
#pragma unroll 4
        for (int j = sl; j < NPTS; j += NSL) {
            float4 q = sT[j];
#pragma unroll
            for (int r = 0; r < RPT; ++r) {
                float t = fmaf(rx[r], q.x, fmaf(ry[r], q.y, fmaf(rz[r], q.z, q.w)));
                m[r] = fmaxf(m[r], t);
            }
        }
#pragma unroll
        for (int r = 0; r < RPT; ++r) {
#pragma unroll
            for (int d = 1; d < NSL; d <<= 1)
                m[r] = fmaxf(m[r], __shfl_xor(m[r], d, 64));
            Ss[r] = 0.f;
        }
#pragma unroll 4
        for (int j = sl; j < NPTS; j += NSL) {
            float4 q = sT[j];
#pragma unroll
            for (int r = 0; r < RPT; ++r) {
                float t = fmaf(rx[r], q.x, fmaf(ry[r], q.y, fmaf(rz[r], q.z, q.w)));
                Ss[r] += fexp2(t - m[r]);
            }
        }
#pragma unroll
        for (int r = 0; r < RPT; ++r) {
#pragma unroll
            for (int d = 1; d < NSL; d <<= 1)
                Ss[r] += __shfl_xor(Ss[r], d, 64);
            ff[r] = FC + pp[r] - EL2 * (m[r] + log2f(Ss[r]));  // all lanes hold ff
        }
        if (sl == 0) {
#pragma unroll
            for (int r = 0; r < RPT; ++r) fdual[dbase + row0 + r] = ff[r];
        }
        batch_barrier(cnt, (++phase) * BPB);

        // ---- stage P-cloud: sT[i] = (px,py,pz, ALPHA*(f_i - |p|^2)) ----
        for (int idx = tid; idx < NPTS; idx += TPB) {
            float x = pb[3*idx], y = pb[3*idx+1], z = pb[3*idx+2];
            float d = fdual[dbase + idx];
            sT[idx] = make_float4(x, y, z, ALPHA * (d - (x*x + y*y + z*z)));
        }
        __syncthreads();
        // ---- g-pass (mirror) ----
#pragma unroll
        for (int r = 0; r < RPT; ++r) m[r] = -3.4e38f;
#pragma unroll 4
        for (int i = sl; i < NPTS; i += NSL) {
            float4 p = sT[i];
#pragma unroll
            for (int r = 0; r < RPT; ++r) {
                float t = fmaf(gx[r], p.x, fmaf(gy[r], p.y, fmaf(gz[r], p.z, p.w)));
                m[r] = fmaxf(m[r], t);
            }
        }
#pragma unroll
        for (int r = 0; r < RPT; ++r) {
#pragma unroll
            for (int d = 1; d < NSL; d <<= 1)
                m[r] = fmaxf(m[r], __shfl_xor(m[r], d, 64));
            Ss[r] = 0.f;
        }
#pragma unroll 4
        for (int i = sl; i < NPTS; i += NSL) {
            float4 p = sT[i];
#pragma unroll
            for (int r = 0; r < RPT; ++r) {
                float t = fmaf(gx[r], p.x, fmaf(gy[r], p.y, fmaf(gz[r], p.z, p.w)));
                Ss[r] += fexp2(t - m[r]);
            }
        }
#pragma unroll
        for (int r = 0; r < RPT; ++r) {
#pragma unroll
            for (int d = 1; d < NSL; d <<= 1)
                Ss[r] += __shfl_xor(Ss[r], d, 64);
            float gval = FC + qq[r] - EL2 * (m[r] + log2f(Ss[r]));
            if (sl == 0) gdual[dbase + row0 + r] = gval;
        }
        batch_barrier(cnt, (++phase) * BPB);
    }

    // ---- final: loss += sum_ij exp2(-ALPHA*C + ALPHA*f_i + ALPHA*g_j) * C ----
    for (int idx = tid; idx < NPTS; idx += TPB) {
        float x = gb[3*idx], y = gb[3*idx+1], z = gb[3*idx+2];
        sT[idx] = make_float4(x, y, z, ALPHA * gdual[dbase + idx]);
    }
    __syncthreads();

    float fa[RPT], pxr[RPT], pyr[RPT], pzr[RPT];
#pragma unroll
    for (int r = 0; r < RPT; ++r) {
        const int i = row0 + r;
        fa[r] = ALPHA * ff[r];               // ff = final f (all lanes hold it)
        pxr[r] = pb[3*i]; pyr[r] = pb[3*i+1]; pzr[r] = pb[3*i+2];
    }
    float acc = 0.f;
#pragma unroll 2
    for (int j = sl; j < NPTS; j += NSL) {
        float4 q = sT[j];
#pragma unroll
        for (int r = 0; r < RPT; ++r) {
            float dx = pxr[r] - q.x, dy = pyr[r] - q.y, dz = pzr[r] - q.z;
            float c  = fmaf(dx, dx, fmaf(dy, dy, dz * dz));
            float k2 = fmaf(-ALPHA, c, fa[r] + q.w);   // log2-domain kernel
            acc = fmaf(fexp2(k2), c, acc);             // P*C (underflow->0 correct)
        }
    }
#pragma unroll
    for (int d = 1; d < NSL; d <<= 1)
        acc += __shfl_xor(acc, d, 64);
    if (sl == 0) atomicAdd(out, acc);
}

extern "C" void kernel_launch(void* const* d_in, const int* in_sizes, int n_in,
                              void* d_out, int out_size, void* d_ws, size_t ws_size,
                              hipStream_t stream) {
    const float* preds = (const float*)d_in[0];
    const float* gts   = (const float*)d_in[1];
    float* out = (float*)d_out;
    float* ws  = (float*)d_ws;   // uses (2*8*2048 + 8*64) floats = 133,120 B

    // Stream-ordered init (capture-safe): duals + counters + out.
    hipMemsetAsync(d_ws, 0, (size_t)(2 * BATCHES * NPTS + BATCHES * 64) * sizeof(float), stream);
    hipMemsetAsync(d_out, 0, (size_t)out_size * sizeof(float), stream);

    void* args[] = { (void*)&preds, (void*)&gts, (void*)&out, (void*)&ws };

    // Primary: 1024 blocks x 256 thr, 32 KB LDS -> 4 blocks/CU (ceiling 5).
    hipError_t e = hipLaunchCooperativeKernel(
        reinterpret_cast<const void*>(&emd_sinkhorn<256, 64, 128>),
        dim3(BATCHES * 128), dim3(256), args, 0, stream);
    if (e != hipSuccess) {
        (void)hipGetLastError();  // clear error state
        // Fallback: R2-proven geometry (512 blocks x 256 thr), same code path.
        hipLaunchCooperativeKernel(
            reinterpret_cast<const void*>(&emd_sinkhorn<256, 32, 64>),
            dim3(BATCHES * 64), dim3(256), args, 0, stream);
    }
}

// Round 10
// 1723.104 us; speedup vs baseline: 2.8349x; 2.8349x over previous
//
#include <hip/hip_runtime.h>

#define BATCHES 8
#define NPTS 2048
#define RPT 4
#define NITERS 50

__device__ __forceinline__ float fexp2(float x) {
#if __has_builtin(__builtin_amdgcn_exp2f)
    return __builtin_amdgcn_exp2f(x);
#else
    return exp2f(x);
#endif
}

// Cross-block dual exchange: per-element relaxed agent-scope atomics.
// These compile to sc0/sc1 (coherence-point) loads/stores -> no L2
// writeback/invalidate needed, L2 stays warm for the point-cloud restage.
__device__ __forceinline__ float ld_dual(const float* p) {
    return __hip_atomic_load(p, __ATOMIC_RELAXED, __HIP_MEMORY_SCOPE_AGENT);
}
__device__ __forceinline__ void st_dual(float* p, float v) {
    __hip_atomic_store(p, v, __ATOMIC_RELAXED, __HIP_MEMORY_SCOPE_AGENT);
}

// Per-batch phase-counter barrier (monotonic counter, no reset race).
// NO __threadfence: __syncthreads() drains each wave's vmcnt (compiler emits
// s_waitcnt vmcnt(0) before s_barrier), so all write-through dual stores have
// reached the coherence point before the leader publishes the counter bump.
// Readers use coherence-point atomic loads, so no acquire-invalidate needed.
__device__ __forceinline__ void batch_barrier(int* cnt, int expected) {
    __syncthreads();   // drains vmcnt of ALL waves in block
    if (threadIdx.x == 0) {
        __hip_atomic_fetch_add(cnt, 1, __ATOMIC_RELAXED, __HIP_MEMORY_SCOPE_AGENT);
        while (__hip_atomic_load(cnt, __ATOMIC_RELAXED, __HIP_MEMORY_SCOPE_AGENT) < expected)
            __builtin_amdgcn_s_sleep(2);
    }
    __syncthreads();
}

// One LDS buffer (32 KB), restaged per half-iteration (L2-hot now that no
// fence invalidates L2). TPB threads, NSL lanes/row-group, BPB blocks/batch.
template<int TPB, int NSL, int BPB>
__global__ __launch_bounds__(TPB, 4)
void emd_sinkhorn(const float* __restrict__ preds, const float* __restrict__ gts,
                  float* __restrict__ out, float* __restrict__ ws)
{
    constexpr int GROUPS = TPB / NSL;    // row-groups per block
    constexpr int RPB = GROUPS * RPT;    // rows per block
    static_assert(RPB * BPB == NPTS, "row coverage");

    // eps = 0.005, N = M = 2048
    const float ALPHA = 288.53900817779268f;     // log2(e)/eps
    const float TWOA  = 2.f * ALPHA;
    const float EL2   = 0.0034657359027997266f;  // eps*ln2
    const float FC    = -0.038123094930796992f;  // eps*log_mu = -eps*ln(2048)

    float* fdual = ws;                       // [BATCHES*NPTS]
    float* gdual = ws + BATCHES * NPTS;      // [BATCHES*NPTS]
    int*   cnts  = (int*)(ws + 2 * BATCHES * NPTS);  // 8 counters, stride 64 ints
    // duals + counters zeroed by host hipMemsetAsync (stream-ordered before us)

    const int batch = blockIdx.x & (BATCHES - 1);
    const int chunk = blockIdx.x >> 3;           // 0..BPB-1
    const int tid = threadIdx.x;
    const int rg  = tid / NSL;                   // row-group
    const int sl  = tid % NSL;                   // j-slice lane
    const int row0 = chunk * RPB + rg * RPT;
    const int dbase = batch * NPTS;
    int* cnt = &cnts[batch * 64];

    __shared__ float4 sT[NPTS];                  // 32 KB: current pass's cloud + a

    const float* pb = preds + (size_t)dbase * 3;
    const float* gb = gts   + (size_t)dbase * 3;

    // Per-thread row constants (points never change), read once from global.
    float rx[RPT], ry[RPT], rz[RPT], pp[RPT], ff[RPT];
    float gx[RPT], gy[RPT], gz[RPT], qq[RPT];
#pragma unroll
    for (int r = 0; r < RPT; ++r) {
        const int i = row0 + r;
        float px = pb[3*i], py = pb[3*i+1], pz = pb[3*i+2];
        rx[r] = TWOA * px; ry[r] = TWOA * py; rz[r] = TWOA * pz;
        pp[r] = px*px + py*py + pz*pz;
        float qx = gb[3*i], qy = gb[3*i+1], qz = gb[3*i+2];
        gx[r] = TWOA * qx; gy[r] = TWOA * qy; gz[r] = TWOA * qz;
        qq[r] = qx*qx + qy*qy + qz*qz;
    }

    int phase = 0;
    float m[RPT], Ss[RPT];

    for (int it = 0; it < NITERS; ++it) {
        // ---- stage G-cloud: sT[j] = (qx,qy,qz, ALPHA*(g_j - |q|^2)) ----
        for (int idx = tid; idx < NPTS; idx += TPB) {
            float x = gb[3*idx], y = gb[3*idx+1], z = gb[3*idx+2];
            float d = ld_dual(&gdual[dbase + idx]);
            sT[idx] = make_float4(x, y, z, ALPHA * (d - (x*x + y*y + z*z)));
        }
        __syncthreads();
        // ---- f-pass: f_i = FC + |p|^2 - EL2*(max_j t + log2 sum 2^(t-max)) ----
#pragma unroll
        for (int r = 0; r < RPT; ++r) m[r] = -3.4e38f;
#pragma unroll 4
        for (int j = sl; j < NPTS; j += NSL) {
            float4 q = sT[j];
#pragma unroll
            for (int r = 0; r < RPT; ++r) {
                float t = fmaf(rx[r], q.x, fmaf(ry[r], q.y, fmaf(rz[r], q.z, q.w)));
                m[r] = fmaxf(m[r], t);
            }
        }
#pragma unroll
        for (int r = 0; r < RPT; ++r) {
#pragma unroll
            for (int d = 1; d < NSL; d <<= 1)
                m[r] = fmaxf(m[r], __shfl_xor(m[r], d, 64));
            Ss[r] = 0.f;
        }
#pragma unroll 4
        for (int j = sl; j < NPTS; j += NSL) {
            float4 q = sT[j];
#pragma unroll
            for (int r = 0; r < RPT; ++r) {
                float t = fmaf(rx[r], q.x, fmaf(ry[r], q.y, fmaf(rz[r], q.z, q.w)));
                Ss[r] += fexp2(t - m[r]);
            }
        }
#pragma unroll
        for (int r = 0; r < RPT; ++r) {
#pragma unroll
            for (int d = 1; d < NSL; d <<= 1)
                Ss[r] += __shfl_xor(Ss[r], d, 64);
            ff[r] = FC + pp[r] - EL2 * (m[r] + log2f(Ss[r]));  // all lanes hold ff
        }
        if (sl == 0) {
#pragma unroll
            for (int r = 0; r < RPT; ++r) st_dual(&fdual[dbase + row0 + r], ff[r]);
        }
        batch_barrier(cnt, (++phase) * BPB);

        // ---- stage P-cloud: sT[i] = (px,py,pz, ALPHA*(f_i - |p|^2)) ----
        for (int idx = tid; idx < NPTS; idx += TPB) {
            float x = pb[3*idx], y = pb[3*idx+1], z = pb[3*idx+2];
            float d = ld_dual(&fdual[dbase + idx]);
            sT[idx] = make_float4(x, y, z, ALPHA * (d - (x*x + y*y + z*z)));
        }
        __syncthreads();
        // ---- g-pass (mirror) ----
#pragma unroll
        for (int r = 0; r < RPT; ++r) m[r] = -3.4e38f;
#pragma unroll 4
        for (int i = sl; i < NPTS; i += NSL) {
            float4 p = sT[i];
#pragma unroll
            for (int r = 0; r < RPT; ++r) {
                float t = fmaf(gx[r], p.x, fmaf(gy[r], p.y, fmaf(gz[r], p.z, p.w)));
                m[r] = fmaxf(m[r], t);
            }
        }
#pragma unroll
        for (int r = 0; r < RPT; ++r) {
#pragma unroll
            for (int d = 1; d < NSL; d <<= 1)
                m[r] = fmaxf(m[r], __shfl_xor(m[r], d, 64));
            Ss[r] = 0.f;
        }
#pragma unroll 4
        for (int i = sl; i < NPTS; i += NSL) {
            float4 p = sT[i];
#pragma unroll
            for (int r = 0; r < RPT; ++r) {
                float t = fmaf(gx[r], p.x, fmaf(gy[r], p.y, fmaf(gz[r], p.z, p.w)));
                Ss[r] += fexp2(t - m[r]);
            }
        }
#pragma unroll
        for (int r = 0; r < RPT; ++r) {
#pragma unroll
            for (int d = 1; d < NSL; d <<= 1)
                Ss[r] += __shfl_xor(Ss[r], d, 64);
            float gval = FC + qq[r] - EL2 * (m[r] + log2f(Ss[r]));
            if (sl == 0) st_dual(&gdual[dbase + row0 + r], gval);
        }
        batch_barrier(cnt, (++phase) * BPB);
    }

    // ---- final: loss += sum_ij exp2(-ALPHA*C + ALPHA*f_i + ALPHA*g_j) * C ----
    for (int idx = tid; idx < NPTS; idx += TPB) {
        float x = gb[3*idx], y = gb[3*idx+1], z = gb[3*idx+2];
        sT[idx] = make_float4(x, y, z, ALPHA * ld_dual(&gdual[dbase + idx]));
    }
    __syncthreads();

    float fa[RPT], pxr[RPT], pyr[RPT], pzr[RPT];
#pragma unroll
    for (int r = 0; r < RPT; ++r) {
        const int i = row0 + r;
        fa[r] = ALPHA * ff[r];               // ff = final f (all lanes hold it)
        pxr[r] = pb[3*i]; pyr[r] = pb[3*i+1]; pzr[r] = pb[3*i+2];
    }
    float acc = 0.f;
#pragma unroll 2
    for (int j = sl; j < NPTS; j += NSL) {
        float4 q = sT[j];
#pragma unroll
        for (int r = 0; r < RPT; ++r) {
            float dx = pxr[r] - q.x, dy = pyr[r] - q.y, dz = pzr[r] - q.z;
            float c  = fmaf(dx, dx, fmaf(dy, dy, dz * dz));
            float k2 = fmaf(-ALPHA, c, fa[r] + q.w);   // log2-domain kernel
            acc = fmaf(fexp2(k2), c, acc);             // P*C (underflow->0 correct)
        }
    }
#pragma unroll
    for (int d = 1; d < NSL; d <<= 1)
        acc += __shfl_xor(acc, d, 64);
    if (sl == 0) atomicAdd(out, acc);
}

extern "C" void kernel_launch(void* const* d_in, const int* in_sizes, int n_in,
                              void* d_out, int out_size, void* d_ws, size_t ws_size,
                              hipStream_t stream) {
    const float* preds = (const float*)d_in[0];
    const float* gts   = (const float*)d_in[1];
    float* out = (float*)d_out;
    float* ws  = (float*)d_ws;   // uses (2*8*2048 + 8*64) floats = 133,120 B

    // Stream-ordered init (capture-safe): duals + counters + out.
    hipMemsetAsync(d_ws, 0, (size_t)(2 * BATCHES * NPTS + BATCHES * 64) * sizeof(float), stream);
    hipMemsetAsync(d_out, 0, (size_t)out_size * sizeof(float), stream);

    void* args[] = { (void*)&preds, (void*)&gts, (void*)&out, (void*)&ws };

    // Primary: 1024 blocks x 256 thr, 32 KB LDS -> 4 blocks/CU (launch-proven R7).
    hipError_t e = hipLaunchCooperativeKernel(
        reinterpret_cast<const void*>(&emd_sinkhorn<256, 64, 128>),
        dim3(BATCHES * 128), dim3(256), args, 0, stream);
    if (e != hipSuccess) {
        (void)hipGetLastError();  // clear error state
        // Fallback: R2-proven geometry (512 blocks x 256 thr), same code path.
        hipLaunchCooperativeKernel(
            reinterpret_cast<const void*>(&emd_sinkhorn<256, 32, 64>),
            dim3(BATCHES * 64), dim3(256), args, 0, stream);
    }
}